// Round 1
// baseline (626.655 us; speedup 1.0000x reference)
//
#include <hip/hip_runtime.h>

#define BLOCK 336
#define GROUPS_PER_BLOCK 33
#define NBLK_PER_WG 8
#define WG_THREADS 256
#define FLOATS_PER_WG (NBLK_PER_WG * BLOCK)      // 2688
#define F4_PER_WG (FLOATS_PER_WG / 4)            // 672
#define GROUPS_PER_WG (NBLK_PER_WG * GROUPS_PER_BLOCK)  // 264

__global__ __launch_bounds__(WG_THREADS)
void softmax336_kernel(const float* __restrict__ in, float* __restrict__ out, int n_floats) {
    __shared__ float4 lds4[F4_PER_WG];
    float* lds = (float*)lds4;

    const int tid = threadIdx.x;
    const long long base = (long long)blockIdx.x * FLOATS_PER_WG;

    // how many floats this WG actually owns (tail guard; n divisible by 4 and 336 here)
    const int n_here = (int)min((long long)FLOATS_PER_WG, (long long)n_floats - base);
    if (n_here <= 0) return;
    const int n4_here = n_here >> 2;
    const int nblk_here = n_here / BLOCK;
    const int ngroups_here = nblk_here * GROUPS_PER_BLOCK;

    // ---- phase 1: coalesced global -> LDS ----
    const float4* __restrict__ src = (const float4*)(in + base);
    for (int i = tid; i < n4_here; i += WG_THREADS)
        lds4[i] = src[i];
    __syncthreads();

    // ---- phase 2: one thread per softmax group ----
    for (int g = tid; g < ngroups_here; g += WG_THREADS) {
        const int blk = g / GROUPS_PER_BLOCK;
        const int idx = g - blk * GROUPS_PER_BLOCK;
        int off, len;
        if (idx < 18)      { off = idx * 11;              len = 11; }  // segs 0,1: 18 groups of 11
        else if (idx < 27) { off = 198 + (idx - 18) * 8;  len = 8;  }  // seg 2:    9 groups of 8
        else               { off = 270 + (idx - 27) * 11; len = 11; }  // seg 3:    6 groups of 11

        float* p = lds + blk * BLOCK + off;

        float v[11];
        float m = -3.0e38f;
#pragma unroll
        for (int k = 0; k < 11; ++k) {
            float x = (k < len) ? p[k] : -3.0e38f;
            v[k] = x;
            m = fmaxf(m, x);
        }
        float s = 0.0f;
#pragma unroll
        for (int k = 0; k < 11; ++k) {
            float e = __expf(v[k] - m);   // k>=len: exp(-huge) -> 0, harmless
            v[k] = e;
            s += e;
        }
        const float r = 1.0f / s;
#pragma unroll
        for (int k = 0; k < 11; ++k) {
            if (k < len) p[k] = v[k] * r;
        }
    }
    __syncthreads();

    // ---- phase 3: coalesced LDS -> global ----
    float4* __restrict__ dst = (float4*)(out + base);
    for (int i = tid; i < n4_here; i += WG_THREADS)
        dst[i] = lds4[i];
}

extern "C" void kernel_launch(void* const* d_in, const int* in_sizes, int n_in,
                              void* d_out, int out_size, void* d_ws, size_t ws_size,
                              hipStream_t stream) {
    const float* x = (const float*)d_in[0];
    float* out = (float*)d_out;
    const int n = in_sizes[0];                 // 32768 * 3024 = 99,090,432
    const int n_wg = (int)((n + (long long)FLOATS_PER_WG - 1) / FLOATS_PER_WG);  // 36864
    softmax336_kernel<<<n_wg, WG_THREADS, 0, stream>>>(x, out, n);
}